// Round 9
// baseline (206.681 us; speedup 1.0000x reference)
//
#include <hip/hip_runtime.h>

typedef __attribute__((ext_vector_type(8))) __bf16 bf16x8;
typedef __attribute__((ext_vector_type(4))) __bf16 bf16x4;
typedef __attribute__((ext_vector_type(4))) float f32x4;
typedef __attribute__((ext_vector_type(16))) float f32x16;

#define BSZ 4
#define CCH 512
#define SEQ 2048
#define NH  8
#define HD  64

__device__ __forceinline__ f32x4 mfma16(bf16x8 a, bf16x8 b, f32x4 c) {
  return __builtin_amdgcn_mfma_f32_16x16x32_bf16(a, b, c, 0, 0, 0);
}
__device__ __forceinline__ f32x16 mfma32(bf16x8 a, bf16x8 b, f32x16 c) {
  return __builtin_amdgcn_mfma_f32_32x32x16_bf16(a, b, c, 0, 0, 0);
}

__device__ __forceinline__ void gload16(const void* g, void* l) {
  __builtin_amdgcn_global_load_lds((const __attribute__((address_space(1))) void*)g,
                                   (__attribute__((address_space(3))) void*)l,
                                   16, 0, 0);
}

__device__ __forceinline__ unsigned cvtpk(float lo, float hi) {
  unsigned r;
  asm("v_cvt_pk_bf16_f32 %0, %1, %2" : "=v"(r) : "v"(lo), "v"(hi));
  return r;
}
__device__ __forceinline__ void pl32swap(unsigned& a, unsigned& b) {
  asm("v_permlane32_swap_b32 %0, %1" : "+v"(a), "+v"(b));
}

#define WAIT_VM(N)                                          \
  asm volatile("s_waitcnt vmcnt(" #N ")" ::: "memory");     \
  __builtin_amdgcn_sched_barrier(0);                        \
  __builtin_amdgcn_s_barrier();

// ---------------- GroupNorm partials (no atomics; 64 partials per batch) ----------------
__global__ __launch_bounds__(256) void gn_partial(const float* __restrict__ x,
                                                  float* __restrict__ stats) {
  int b = blockIdx.y;
  const float4* xb = (const float4*)(x + ((size_t)b << 20) + (size_t)blockIdx.x * 16384);
  int tid = threadIdx.x;
  float s = 0.f, sq = 0.f;
#pragma unroll
  for (int i = 0; i < 16; ++i) {
    float4 v = xb[i * 256 + tid];
    s  += v.x + v.y + v.z + v.w;
    sq += v.x * v.x + v.y * v.y + v.z * v.z + v.w * v.w;
  }
#pragma unroll
  for (int o = 32; o > 0; o >>= 1) { s += __shfl_down(s, o); sq += __shfl_down(sq, o); }
  __shared__ float ls[4], lq[4];
  int w = tid >> 6;
  if ((tid & 63) == 0) { ls[w] = s; lq[w] = sq; }
  __syncthreads();
  if (tid == 0) {
    stats[b * 64 + blockIdx.x]       = ls[0] + ls[1] + ls[2] + ls[3];
    stats[256 + b * 64 + blockIdx.x] = lq[0] + lq[1] + lq[2] + lq[3];
  }
}

// ---------------- normalize + transpose to [B*S, C] bf16 (gn_final fused) ----------------
__global__ __launch_bounds__(256) void norm_tr(const float* __restrict__ x,
                                               const float* __restrict__ gw,
                                               const float* __restrict__ gb,
                                               const float* __restrict__ stats,
                                               __bf16* __restrict__ h) {
  int s0 = blockIdx.x * 64, c0 = blockIdx.y * 64, b = blockIdx.z;
  float sacc = 0.f, qacc = 0.f;
  for (int i = 0; i < 64; ++i) {
    sacc += stats[b * 64 + i];
    qacc += stats[256 + b * 64 + i];
  }
  const float inv_n = 1.0f / 1048576.f;
  float mean = sacc * inv_n;
  float rstd = rsqrtf(qacc * inv_n - mean * mean + 1e-5f);
  const float* xb = x + ((size_t)b << 20);
  __shared__ __align__(16) __bf16 tile[64][72];
  int tid = threadIdx.x;
#pragma unroll
  for (int j = 0; j < 16; ++j) {
    int e = tid + j * 256;
    int cl = e >> 6, sl = e & 63;
    float vv = xb[(size_t)(c0 + cl) * 2048 + s0 + sl];
    float hn = (vv - mean) * rstd * gw[c0 + cl] + gb[c0 + cl];
    tile[cl][sl] = (__bf16)hn;
  }
  __syncthreads();
#pragma unroll
  for (int j = 0; j < 2; ++j) {
    int row = (tid >> 3) + j * 32;  // s-local
    int cg = tid & 7;
    bf16x8 pk;
#pragma unroll
    for (int e = 0; e < 8; ++e) pk[e] = tile[cg * 8 + e][row];
    *(bf16x8*)&h[(size_t)((b << 11) + s0 + row) * 512 + c0 + cg * 8] = pk;
  }
}

// ---------------- weights fp32 -> bf16 ----------------
__global__ __launch_bounds__(256) void wcvt(const float* __restrict__ wq, const float* __restrict__ wk,
                                            const float* __restrict__ wv, const float* __restrict__ wo,
                                            __bf16* __restrict__ out) {
  int i = blockIdx.x * 256 + threadIdx.x;  // 0..262143
  out[i]          = (__bf16)wq[i];
  out[262144 + i] = (__bf16)wk[i];
  out[524288 + i] = (__bf16)wv[i];
  out[786432 + i] = (__bf16)wo[i];
}

// ---------------- QKV GEMM: [8192,512] x [512,512]^T, BK=32, 2-buf 2-phase ----------------
// LDS ~34.8KB -> 4 blocks/CU allowed; all 768 blocks co-resident (3/CU).
// z==2 writes V^T [B,H,D,S] via LDS transpose (coalesced stores).
__global__ __launch_bounds__(256) void gemm_qkv(const __bf16* __restrict__ A, const __bf16* __restrict__ Wb,
                                                const float* __restrict__ bq, const float* __restrict__ bk,
                                                const float* __restrict__ bvv,
                                                __bf16* __restrict__ oq, __bf16* __restrict__ ok,
                                                __bf16* __restrict__ ovt) {
  __shared__ __align__(16) union QU {
    struct SS { __bf16 a[2][4096]; __bf16 b[2][4096]; } s;  // [128 rows][32 cols] each
    __bf16 t[128 * 136];
  } u;
  int z = blockIdx.z;
  const __bf16* W = Wb + (size_t)z * 262144;
  const float* bias = z == 0 ? bq : (z == 1 ? bk : bvv);
  int tid = threadIdx.x, wid = tid >> 6, l = tid & 63;
  int m0 = blockIdx.x * 128, n0 = blockIdx.y * 128;
  int wm = (wid >> 1) * 64, wn = (wid & 1) * 64;
  int l16 = l & 15, lg = l >> 4;
  f32x4 zero = {0.f, 0.f, 0.f, 0.f};
  f32x4 acc[4][4];
#pragma unroll
  for (int mt = 0; mt < 4; ++mt)
#pragma unroll
    for (int nt = 0; nt < 4; ++nt) acc[mt][nt] = zero;

  int srow = wid * 32 + (l >> 2);                 // row within 128-tile (plus t*16)
  int scol = ((l & 3) ^ ((l >> 3) & 3)) * 8;      // pre-swizzled global k-chunk
  int rs = (lg ^ ((l16 >> 1) & 3)) * 8;           // read-side phys slot

  auto STG = [&](int buf, int k0) {
#pragma unroll
    for (int t = 0; t < 2; ++t) {
      gload16(A + (size_t)(m0 + srow + t * 16) * 512 + k0 + scol, &u.s.a[buf][(wid * 32 + t * 16) * 32]);
      gload16(W + (size_t)(n0 + srow + t * 16) * 512 + k0 + scol, &u.s.b[buf][(wid * 32 + t * 16) * 32]);
    }
  };
  auto CMP = [&](int buf) {
    bf16x8 af[4], bfr[4];
#pragma unroll
    for (int mt = 0; mt < 4; ++mt) af[mt] = *(const bf16x8*)&u.s.a[buf][(wm + mt * 16 + l16) * 32 + rs];
#pragma unroll
    for (int nt = 0; nt < 4; ++nt) bfr[nt] = *(const bf16x8*)&u.s.b[buf][(wn + nt * 16 + l16) * 32 + rs];
    __builtin_amdgcn_s_setprio(1);
#pragma unroll
    for (int mt = 0; mt < 4; ++mt)
#pragma unroll
      for (int nt = 0; nt < 4; ++nt) acc[mt][nt] = mfma16(af[mt], bfr[nt], acc[mt][nt]);
    __builtin_amdgcn_s_setprio(0);
  };

  STG(0, 0);
  WAIT_VM(0);
#pragma unroll
  for (int t = 0; t < 16; ++t) {
    if (t < 15) STG((t + 1) & 1, (t + 1) * 32);   // loads fly under this tile's MFMA
    CMP(t & 1);
    if (t < 15) { WAIT_VM(0); }
  }

  if (z < 2) {
    __bf16* out = z == 0 ? oq : ok;
#pragma unroll
    for (int nt = 0; nt < 4; ++nt) {
      int col = n0 + wn + nt * 16 + l16;
      float bb = bias[col];
#pragma unroll
      for (int mt = 0; mt < 4; ++mt)
#pragma unroll
        for (int r = 0; r < 4; ++r)
          out[(size_t)(m0 + wm + mt * 16 + lg * 4 + r) * 512 + col] = (__bf16)(acc[mt][nt][r] + bb);
    }
  } else {
    __syncthreads();
    // stage transposed: t[col][m], stride 136 (keeps 16B alignment for b128)
#pragma unroll
    for (int nt = 0; nt < 4; ++nt) {
      int col = wn + nt * 16 + l16;
      float bb = bias[n0 + col];
#pragma unroll
      for (int mt = 0; mt < 4; ++mt)
#pragma unroll
        for (int r = 0; r < 4; ++r)
          u.t[col * 136 + wm + mt * 16 + lg * 4 + r] = (__bf16)(acc[mt][nt][r] + bb);
    }
    __syncthreads();
    int bI = m0 >> 11, sbase = m0 & 2047;
#pragma unroll
    for (int p = 0; p < 8; ++p) {
      int row = (tid >> 4) + p * 16;     // local col of C = d index
      int ck = tid & 15;
      bf16x8 v = *(const bf16x8*)&u.t[row * 136 + ck * 8];
      int colg = n0 + row;
      int hd = colg >> 6, dd = colg & 63;
      *(bf16x8*)&ovt[((size_t)((bI * 8 + hd) * 64 + dd)) * 2048 + sbase + ck * 8] = v;
    }
  }
}

// ---------------- flash attention, split-KV x2: unnormalized f32 partials ----------------
// z = (half<<2)|b. Block: 4 waves x 32 q-rows, KV range [half*1024, half*1024+1024).
// No-max softmax (additive partials). 2-buf LDS (32KB) -> with grid 1024 = 4 blocks/CU,
// 16 waves/CU (2x occupancy vs pre-split).
__global__ __launch_bounds__(256) void attn(const __bf16* __restrict__ q, const __bf16* __restrict__ k,
                                            const __bf16* __restrict__ vt,
                                            float* __restrict__ opart, float* __restrict__ lpart) {
  const float C2 = 0.18033688011f;  // (1/8) * log2(e)
  int tid = threadIdx.x, w = tid >> 6, l = tid & 63;
  int q0w = blockIdx.x * 128 + w * 32;
  int hh = blockIdx.y;
  int z = blockIdx.z, b = z & 3, half = z >> 2;
  int kvbase = half * 1024;
  int l31 = l & 31, hi = l >> 5;

  __shared__ __align__(16) __bf16 smem[2][8192];  // per buf: K[64][64] | V[64][64]

  bf16x8 qf[4];
  {
    const __bf16* qrow = q + ((size_t)((b << 11) + q0w + l31)) * 512 + hh * 64 + hi * 8;
#pragma unroll
    for (int dt = 0; dt < 4; ++dt) qf[dt] = *(const bf16x8*)&qrow[dt * 16];
  }
  bf16x8 ones;
#pragma unroll
  for (int j = 0; j < 8; ++j) ones[j] = (__bf16)1.0f;

  const __bf16* kbase = k + ((size_t)(b << 11)) * 512 + hh * 64;
  const __bf16* vtb = vt + ((size_t)((b * 8 + hh) * 64)) * 2048;

  f32x16 zero16 = {};
  f32x16 o2[2];
  o2[0] = zero16; o2[1] = zero16;
  f32x16 facc = zero16;           // MFMA row-sum accumulator (all regs equal per lane)

  int rloc = l >> 3;              // 0..7 row within chunk
  int swz = (l31 & 7);            // read-side XOR (row&7)
  int q3 = (l31 >> 3) & 3;        // read-side XOR ((row>>3)&3)

  auto STAGE = [&](int buf, int kv0) {
#pragma unroll
    for (int i = 0; i < 4; ++i) {
      int c = w * 4 + i;                   // 0..15; 0-7 = K chunks, 8-15 = V chunks
      int cc = c & 7;
      int row = cc * 8 + rloc;             // 0..63
      int sg = (((l & 7) ^ rloc ^ (cc & 3))) * 8;
      if (c < 8) {
        gload16(kbase + (size_t)(kv0 + row) * 512 + sg, &smem[buf][c * 512]);
      } else {
        gload16(vtb + (size_t)row * 2048 + kv0 + sg, &smem[buf][4096 + cc * 512]);
      }
    }
  };

  auto COMPUTE = [&](int buf) {
    const __bf16* Kt = &smem[buf][0];
    const __bf16* Vts = &smem[buf][4096];
    f32x16 sc[2];
#pragma unroll
    for (int kb = 0; kb < 2; ++kb) {
      sc[kb] = zero16;
      int r = kb * 32 + l31;
      __builtin_amdgcn_s_setprio(1);
#pragma unroll
      for (int dt = 0; dt < 4; ++dt) {
        bf16x8 kf = *(const bf16x8*)&Kt[r * 64 + ((dt * 2 + hi) ^ swz ^ q3) * 8];
        sc[kb] = mfma32(kf, qf[dt], sc[kb]);
      }
      __builtin_amdgcn_s_setprio(0);
    }

    // no-max softmax: GroupNorm'ed inputs keep scores bounded; exp2 directly.
#pragma unroll
    for (int kb = 0; kb < 2; ++kb)
#pragma unroll
      for (int r = 0; r < 16; ++r)
        sc[kb][r] = exp2f(sc[kb][r] * C2);

#pragma unroll
    for (int t = 0; t < 4; ++t) {
      int kb = t >> 1, h8 = (t & 1) * 8;
      unsigned u0 = cvtpk(sc[kb][h8 + 0], sc[kb][h8 + 1]);
      unsigned u1 = cvtpk(sc[kb][h8 + 2], sc[kb][h8 + 3]);
      unsigned u2 = cvtpk(sc[kb][h8 + 4], sc[kb][h8 + 5]);
      unsigned u3 = cvtpk(sc[kb][h8 + 6], sc[kb][h8 + 7]);
      pl32swap(u0, u2);
      pl32swap(u1, u3);
      union { unsigned u[4]; bf16x8 v; } pb;
      pb.u[0] = u0; pb.u[1] = u1; pb.u[2] = u2; pb.u[3] = u3;
      __builtin_amdgcn_s_setprio(1);
      facc = mfma32(ones, pb.v, facc);   // row-sum of P on the MFMA pipe
#pragma unroll
      for (int dblk = 0; dblk < 2; ++dblk) {
        int r = dblk * 32 + l31;
        bf16x8 vf = *(const bf16x8*)&Vts[r * 64 + ((t * 2 + hi) ^ swz ^ q3) * 8];
        o2[dblk] = mfma32(vf, pb.v, o2[dblk]);
      }
      __builtin_amdgcn_s_setprio(0);
    }
  };

  STAGE(0, kvbase);
  __syncthreads();
  int cur = 0;
#pragma unroll 1
  for (int t = 0; t < 16; ++t) {
    if (t + 1 < 16) STAGE(cur ^ 1, kvbase + (t + 1) * 64);
    COMPUTE(cur);
    __syncthreads();
    cur ^= 1;
  }

  // --- epilogue: f32 O^T -> O via per-wave LDS region (8KB each), unnormalized store ---
  float* T = (float*)&smem[0][0] + w * 2048;  // 32 rows x 64 f32
  int swzq = (l31 & 7) * 8;
#pragma unroll
  for (int dblk = 0; dblk < 2; ++dblk)
#pragma unroll
    for (int g = 0; g < 4; ++g) {
      float4 v4;
      v4.x = o2[dblk][g * 4 + 0]; v4.y = o2[dblk][g * 4 + 1];
      v4.z = o2[dblk][g * 4 + 2]; v4.w = o2[dblk][g * 4 + 3];
      int d4 = dblk * 32 + g * 8 + hi * 4;
      *(float4*)&T[l31 * 64 + (d4 ^ swzq)] = v4;
    }
  int qr = l >> 1, hf = l & 1;
  int swzr = (qr & 7) * 8;
  float* orow = opart + ((size_t)half << 22) + (size_t)((b << 11) + q0w + qr) * 512 + hh * 64;
#pragma unroll
  for (int m = 0; m < 8; ++m) {
    int c = hf * 32 + m * 4;
    float4 v = *(const float4*)&T[qr * 64 + (c ^ swzr)];
    *(float4*)&orow[c] = v;
  }
  if (hi == 0)
    lpart[((size_t)(half * 4 + b) * 8 + hh) * 2048 + q0w + l31] = facc[0];
}

// ---------------- combine split-KV partials -> normalized bf16 ao ----------------
__global__ __launch_bounds__(256) void combine(const float* __restrict__ opart,
                                               const float* __restrict__ lpart,
                                               __bf16* __restrict__ ao) {
  size_t e = ((size_t)blockIdx.x * 256 + threadIdx.x) * 8;  // over 4M elements
  int row = (int)(e >> 9);
  int c = (int)(e & 511);
  int b = row >> 11, s = row & 2047, hh = c >> 6;
  float l0 = lpart[((size_t)b * 8 + hh) * 2048 + s];
  float l1 = lpart[((size_t)(4 + b) * 8 + hh) * 2048 + s];
  float inv = 1.0f / (l0 + l1);
  float4 a0 = *(const float4*)&opart[e];
  float4 a1 = *(const float4*)&opart[(1ull << 22) + e];
  float4 c0 = *(const float4*)&opart[e + 4];
  float4 c1 = *(const float4*)&opart[(1ull << 22) + e + 4];
  bf16x8 o;
  o[0] = (__bf16)((a0.x + a1.x) * inv);
  o[1] = (__bf16)((a0.y + a1.y) * inv);
  o[2] = (__bf16)((a0.z + a1.z) * inv);
  o[3] = (__bf16)((a0.w + a1.w) * inv);
  o[4] = (__bf16)((c0.x + c1.x) * inv);
  o[5] = (__bf16)((c0.y + c1.y) * inv);
  o[6] = (__bf16)((c0.z + c1.z) * inv);
  o[7] = (__bf16)((c0.w + c1.w) * inv);
  *(bf16x8*)&ao[e] = o;
}

// ---------------- out projection + residual + transpose to [B,C,S], BK=64 2-phase ----------------
__global__ __launch_bounds__(256) void gemm_proj(const __bf16* __restrict__ A, const __bf16* __restrict__ W,
                                                 const float* __restrict__ bias,
                                                 const float* __restrict__ resid,
                                                 float* __restrict__ outp) {
  __shared__ __align__(16) union UU {
    struct SS { __bf16 a[2][8192]; __bf16 b[2][8192]; } s;
    float st[128 * 129];
  } u;
  int tid = threadIdx.x, wid = tid >> 6, l = tid & 63;
  int m0 = blockIdx.x * 128, n0 = blockIdx.y * 128;
  int wm = (wid >> 1) * 64, wn = (wid & 1) * 64;
  int l16 = l & 15, lg = l >> 4;
  f32x4 zero = {0.f, 0.f, 0.f, 0.f};
  f32x4 acc[4][4];
#pragma unroll
  for (int mt = 0; mt < 4; ++mt)
#pragma unroll
    for (int nt = 0; nt < 4; ++nt) acc[mt][nt] = zero;

  int rloc = l >> 3;
  int sg = ((l & 7) ^ rloc) * 8;
  int rdx = l16 & 7;

  auto STG = [&](int buf, int k0) {
#pragma unroll
    for (int t = 0; t < 4; ++t) {
      int row = wid * 32 + t * 8;
      gload16(A + (size_t)(m0 + row + rloc) * 512 + k0 + sg, &u.s.a[buf][row * 64]);
      gload16(W + (size_t)(n0 + row + rloc) * 512 + k0 + sg, &u.s.b[buf][row * 64]);
    }
  };
  auto CMP = [&](int buf) {
#pragma unroll
    for (int kk = 0; kk < 2; ++kk) {
      bf16x8 af[4], bfr[4];
#pragma unroll
      for (int mt = 0; mt < 4; ++mt)
        af[mt] = *(const bf16x8*)&u.s.a[buf][(wm + mt * 16 + l16) * 64 + (((kk * 4 + lg) ^ rdx) * 8)];
#pragma unroll
      for (int nt = 0; nt < 4; ++nt)
        bfr[nt] = *(const bf16x8*)&u.s.b[buf][(wn + nt * 16 + l16) * 64 + (((kk * 4 + lg) ^ rdx) * 8)];
      __builtin_amdgcn_s_setprio(1);
#pragma unroll
      for (int mt = 0; mt < 4; ++mt)
#pragma unroll
        for (int nt = 0; nt < 4; ++nt) acc[mt][nt] = mfma16(af[mt], bfr[nt], acc[mt][nt]);
      __builtin_amdgcn_s_setprio(0);
    }
  };

  STG(0, 0);
  WAIT_VM(0);
#pragma unroll
  for (int t = 0; t < 8; ++t) {
    if (t < 7) STG((t + 1) & 1, (t + 1) * 64);
    CMP(t & 1);
    if (t < 7) { WAIT_VM(0); }
  }

  __syncthreads();
#pragma unroll
  for (int nt = 0; nt < 4; ++nt) {
    int col = wn + nt * 16 + l16;
    float bb = bias[n0 + col];
#pragma unroll
    for (int mt = 0; mt < 4; ++mt)
#pragma unroll
      for (int r = 0; r < 4; ++r)
        u.st[(wm + mt * 16 + lg * 4 + r) * 129 + col] = acc[mt][nt][r] + bb;
  }
  __syncthreads();
  int b = m0 >> 11;
  int sbase = m0 & 2047;
  const float* rb = resid + ((size_t)b << 20);
  float* ob = outp + ((size_t)b << 20);
#pragma unroll
  for (int it = 0; it < 16; ++it) {
    int c = (tid >> 5) + it * 8;  // 0..127 local col
    int s4 = (tid & 31) * 4;      // 0..124 local row
    float4 r4 = *(const float4*)&rb[(size_t)(n0 + c) * 2048 + sbase + s4];
    float4 o4;
    o4.x = u.st[(s4 + 0) * 129 + c] + r4.x;
    o4.y = u.st[(s4 + 1) * 129 + c] + r4.y;
    o4.z = u.st[(s4 + 2) * 129 + c] + r4.z;
    o4.w = u.st[(s4 + 3) * 129 + c] + r4.w;
    *(float4*)&ob[(size_t)(n0 + c) * 2048 + sbase + s4] = o4;
  }
}

extern "C" void kernel_launch(void* const* d_in, const int* in_sizes, int n_in,
                              void* d_out, int out_size, void* d_ws, size_t ws_size,
                              hipStream_t stream) {
  const float* x   = (const float*)d_in[0];
  const float* gw  = (const float*)d_in[1];
  const float* gb  = (const float*)d_in[2];
  const float* wqf = (const float*)d_in[3];
  const float* bqf = (const float*)d_in[4];
  const float* wkf = (const float*)d_in[5];
  const float* bkf = (const float*)d_in[6];
  const float* wvf = (const float*)d_in[7];
  const float* bvf = (const float*)d_in[8];
  const float* wof = (const float*)d_in[9];
  const float* bof = (const float*)d_in[10];
  float* outp = (float*)d_out;

  char* ws = (char*)d_ws;
  float* stats = (float*)ws;              // 512 floats of partials
  const size_t MAT = (size_t)8192 * 512;  // elements
  __bf16* h  = (__bf16*)(ws + 4096);
  __bf16* q  = h + MAT;
  __bf16* k  = q + MAT;
  __bf16* vt = k + MAT;
  __bf16* ao = vt + MAT;
  __bf16* wB = ao + MAT;                  // 4 x 512*512
  float* opart = (float*)(wB + 4 * 262144);  // 2 x 4M f32
  float* lpart = opart + 2 * MAT;            // 2 x 64K f32

  gn_partial<<<dim3(64, 4), 256, 0, stream>>>(x, stats);
  norm_tr<<<dim3(32, 8, 4), 256, 0, stream>>>(x, gw, gb, stats, h);
  wcvt<<<1024, 256, 0, stream>>>(wqf, wkf, wvf, wof, wB);
  gemm_qkv<<<dim3(64, 4, 3), 256, 0, stream>>>(h, wB, bqf, bkf, bvf, q, k, vt);
  attn<<<dim3(16, 8, 8), 256, 0, stream>>>(q, k, vt, opart, lpart);
  combine<<<2048, 256, 0, stream>>>(opart, lpart, ao);
  gemm_proj<<<dim3(64, 4), 256, 0, stream>>>(ao, wB + 3 * 262144, bof, x, outp);
}

// Round 10
// 191.710 us; speedup vs baseline: 1.0781x; 1.0781x over previous
//
#include <hip/hip_runtime.h>

typedef __attribute__((ext_vector_type(8))) __bf16 bf16x8;
typedef __attribute__((ext_vector_type(4))) __bf16 bf16x4;
typedef __attribute__((ext_vector_type(4))) float f32x4;
typedef __attribute__((ext_vector_type(16))) float f32x16;

#define BSZ 4
#define CCH 512
#define SEQ 2048
#define NH  8
#define HD  64

__device__ __forceinline__ f32x4 mfma16(bf16x8 a, bf16x8 b, f32x4 c) {
  return __builtin_amdgcn_mfma_f32_16x16x32_bf16(a, b, c, 0, 0, 0);
}
__device__ __forceinline__ f32x16 mfma32(bf16x8 a, bf16x8 b, f32x16 c) {
  return __builtin_amdgcn_mfma_f32_32x32x16_bf16(a, b, c, 0, 0, 0);
}

__device__ __forceinline__ void gload16(const void* g, void* l) {
  __builtin_amdgcn_global_load_lds((const __attribute__((address_space(1))) void*)g,
                                   (__attribute__((address_space(3))) void*)l,
                                   16, 0, 0);
}

__device__ __forceinline__ unsigned cvtpk(float lo, float hi) {
  unsigned r;
  asm("v_cvt_pk_bf16_f32 %0, %1, %2" : "=v"(r) : "v"(lo), "v"(hi));
  return r;
}
__device__ __forceinline__ void pl32swap(unsigned& a, unsigned& b) {
  asm("v_permlane32_swap_b32 %0, %1" : "+v"(a), "+v"(b));
}

#define WAIT_VM(N)                                          \
  asm volatile("s_waitcnt vmcnt(" #N ")" ::: "memory");     \
  __builtin_amdgcn_sched_barrier(0);                        \
  __builtin_amdgcn_s_barrier();

// ---------------- GroupNorm partials (no atomics; 64 partials per batch) ----------------
__global__ __launch_bounds__(256) void gn_partial(const float* __restrict__ x,
                                                  float* __restrict__ stats) {
  int b = blockIdx.y;
  const float4* xb = (const float4*)(x + ((size_t)b << 20) + (size_t)blockIdx.x * 16384);
  int tid = threadIdx.x;
  float s = 0.f, sq = 0.f;
#pragma unroll
  for (int i = 0; i < 16; ++i) {
    float4 v = xb[i * 256 + tid];
    s  += v.x + v.y + v.z + v.w;
    sq += v.x * v.x + v.y * v.y + v.z * v.z + v.w * v.w;
  }
#pragma unroll
  for (int o = 32; o > 0; o >>= 1) { s += __shfl_down(s, o); sq += __shfl_down(sq, o); }
  __shared__ float ls[4], lq[4];
  int w = tid >> 6;
  if ((tid & 63) == 0) { ls[w] = s; lq[w] = sq; }
  __syncthreads();
  if (tid == 0) {
    stats[b * 64 + blockIdx.x]       = ls[0] + ls[1] + ls[2] + ls[3];
    stats[256 + b * 64 + blockIdx.x] = lq[0] + lq[1] + lq[2] + lq[3];
  }
}

// ---------------- normalize + transpose to [B*S, C] bf16 (gn_final fused) ----------------
__global__ __launch_bounds__(256) void norm_tr(const float* __restrict__ x,
                                               const float* __restrict__ gw,
                                               const float* __restrict__ gb,
                                               const float* __restrict__ stats,
                                               __bf16* __restrict__ h) {
  int s0 = blockIdx.x * 64, c0 = blockIdx.y * 64, b = blockIdx.z;
  float sacc = 0.f, qacc = 0.f;
  for (int i = 0; i < 64; ++i) {
    sacc += stats[b * 64 + i];
    qacc += stats[256 + b * 64 + i];
  }
  const float inv_n = 1.0f / 1048576.f;
  float mean = sacc * inv_n;
  float rstd = rsqrtf(qacc * inv_n - mean * mean + 1e-5f);
  const float* xb = x + ((size_t)b << 20);
  __shared__ __align__(16) __bf16 tile[64][72];
  int tid = threadIdx.x;
#pragma unroll
  for (int j = 0; j < 16; ++j) {
    int e = tid + j * 256;
    int cl = e >> 6, sl = e & 63;
    float vv = xb[(size_t)(c0 + cl) * 2048 + s0 + sl];
    float hn = (vv - mean) * rstd * gw[c0 + cl] + gb[c0 + cl];
    tile[cl][sl] = (__bf16)hn;
  }
  __syncthreads();
#pragma unroll
  for (int j = 0; j < 2; ++j) {
    int row = (tid >> 3) + j * 32;  // s-local
    int cg = tid & 7;
    bf16x8 pk;
#pragma unroll
    for (int e = 0; e < 8; ++e) pk[e] = tile[cg * 8 + e][row];
    *(bf16x8*)&h[(size_t)((b << 11) + s0 + row) * 512 + c0 + cg * 8] = pk;
  }
}

// ---------------- weights fp32 -> bf16 ----------------
__global__ __launch_bounds__(256) void wcvt(const float* __restrict__ wq, const float* __restrict__ wk,
                                            const float* __restrict__ wv, const float* __restrict__ wo,
                                            __bf16* __restrict__ out) {
  int i = blockIdx.x * 256 + threadIdx.x;  // 0..262143
  out[i]          = (__bf16)wq[i];
  out[262144 + i] = (__bf16)wk[i];
  out[524288 + i] = (__bf16)wv[i];
  out[786432 + i] = (__bf16)wo[i];
}

// ---------------- QKV GEMM: [8192,512] x [512,512]^T, BK=32, 3-buf counted pipeline ----------------
// z==2 writes V^T [B,H,D,S] via LDS transpose (coalesced stores).
__global__ __launch_bounds__(256) void gemm_qkv(const __bf16* __restrict__ A, const __bf16* __restrict__ Wb,
                                                const float* __restrict__ bq, const float* __restrict__ bk,
                                                const float* __restrict__ bvv,
                                                __bf16* __restrict__ oq, __bf16* __restrict__ ok,
                                                __bf16* __restrict__ ovt) {
  __shared__ __align__(16) union QU {
    struct SS { __bf16 a[3][4096]; __bf16 b[3][4096]; } s;
    __bf16 t[128 * 136];
  } u;
  int z = blockIdx.z;
  const __bf16* W = Wb + (size_t)z * 262144;
  const float* bias = z == 0 ? bq : (z == 1 ? bk : bvv);
  int tid = threadIdx.x, wid = tid >> 6, l = tid & 63;
  int m0 = blockIdx.x * 128, n0 = blockIdx.y * 128;
  int wm = (wid >> 1) * 64, wn = (wid & 1) * 64;
  int l16 = l & 15, lg = l >> 4;
  f32x4 zero = {0.f, 0.f, 0.f, 0.f};
  f32x4 acc[4][4];
#pragma unroll
  for (int mt = 0; mt < 4; ++mt)
#pragma unroll
    for (int nt = 0; nt < 4; ++nt) acc[mt][nt] = zero;

  int srow = wid * 32 + (l >> 2);                 // row within 128-tile (plus t*16)
  int scol = ((l & 3) ^ ((l >> 3) & 3)) * 8;      // pre-swizzled global k-chunk
  int rs = (lg ^ ((l16 >> 1) & 3)) * 8;           // read-side phys slot

  auto STG = [&](int buf, int k0) {
#pragma unroll
    for (int t = 0; t < 2; ++t) {
      gload16(A + (size_t)(m0 + srow + t * 16) * 512 + k0 + scol, &u.s.a[buf][(wid * 32 + t * 16) * 32]);
      gload16(W + (size_t)(n0 + srow + t * 16) * 512 + k0 + scol, &u.s.b[buf][(wid * 32 + t * 16) * 32]);
    }
  };
  auto CMP = [&](int buf) {
    bf16x8 af[4], bfr[4];
#pragma unroll
    for (int mt = 0; mt < 4; ++mt) af[mt] = *(const bf16x8*)&u.s.a[buf][(wm + mt * 16 + l16) * 32 + rs];
#pragma unroll
    for (int nt = 0; nt < 4; ++nt) bfr[nt] = *(const bf16x8*)&u.s.b[buf][(wn + nt * 16 + l16) * 32 + rs];
    __builtin_amdgcn_s_setprio(1);
#pragma unroll
    for (int mt = 0; mt < 4; ++mt)
#pragma unroll
      for (int nt = 0; nt < 4; ++nt) acc[mt][nt] = mfma16(af[mt], bfr[nt], acc[mt][nt]);
    __builtin_amdgcn_s_setprio(0);
  };

  STG(0, 0); STG(1, 32);
  int bc = 0, sb = 2;
  for (int t = 0; t < 15; ++t) {
    WAIT_VM(4);
    if (t < 14) { STG(sb, (t + 2) * 32); sb = sb == 2 ? 0 : sb + 1; }
    CMP(bc); bc = bc == 2 ? 0 : bc + 1;
  }
  WAIT_VM(0);
  CMP(bc);

  if (z < 2) {
    __bf16* out = z == 0 ? oq : ok;
#pragma unroll
    for (int nt = 0; nt < 4; ++nt) {
      int col = n0 + wn + nt * 16 + l16;
      float bb = bias[col];
#pragma unroll
      for (int mt = 0; mt < 4; ++mt)
#pragma unroll
        for (int r = 0; r < 4; ++r)
          out[(size_t)(m0 + wm + mt * 16 + lg * 4 + r) * 512 + col] = (__bf16)(acc[mt][nt][r] + bb);
    }
  } else {
    __syncthreads();
    // stage transposed: t[col][m], stride 136 (keeps 16B alignment for b128)
#pragma unroll
    for (int nt = 0; nt < 4; ++nt) {
      int col = wn + nt * 16 + l16;
      float bb = bias[n0 + col];
#pragma unroll
      for (int mt = 0; mt < 4; ++mt)
#pragma unroll
        for (int r = 0; r < 4; ++r)
          u.t[col * 136 + wm + mt * 16 + lg * 4 + r] = (__bf16)(acc[mt][nt][r] + bb);
    }
    __syncthreads();
    int bI = m0 >> 11, sbase = m0 & 2047;
#pragma unroll
    for (int p = 0; p < 8; ++p) {
      int row = (tid >> 4) + p * 16;     // local col of C = d index
      int ck = tid & 15;
      bf16x8 v = *(const bf16x8*)&u.t[row * 136 + ck * 8];
      int colg = n0 + row;
      int hd = colg >> 6, dd = colg & 63;
      *(bf16x8*)&ovt[((size_t)((bI * 8 + hd) * 64 + dd)) * 2048 + sbase + ck * 8] = v;
    }
  }
}

// ---------------- flash attention: LDS-staged K/V, 3-buf counted-vmcnt, MFMA row-sum ----------------
__global__ __launch_bounds__(256) void attn(const __bf16* __restrict__ q, const __bf16* __restrict__ k,
                                            const __bf16* __restrict__ vt, __bf16* __restrict__ ao) {
  const float C2 = 0.18033688011f;  // (1/8) * log2(e)
  const float THR = 8.0f;           // defer-max threshold (log2 units)
  int tid = threadIdx.x, w = tid >> 6, l = tid & 63;
  int q0w = blockIdx.x * 128 + w * 32;
  int hh = blockIdx.y, b = blockIdx.z;
  int l31 = l & 31, hi = l >> 5;

  __shared__ __align__(16) __bf16 smem[3][8192];  // per buf: K[64][64] | V[64][64]

  bf16x8 qf[4];
  {
    const __bf16* qrow = q + ((size_t)((b << 11) + q0w + l31)) * 512 + hh * 64 + hi * 8;
#pragma unroll
    for (int dt = 0; dt < 4; ++dt) qf[dt] = *(const bf16x8*)&qrow[dt * 16];
  }
  bf16x8 ones;
#pragma unroll
  for (int j = 0; j < 8; ++j) ones[j] = (__bf16)1.0f;

  const __bf16* kbase = k + ((size_t)(b << 11)) * 512 + hh * 64;
  const __bf16* vtb = vt + ((size_t)((b * 8 + hh) * 64)) * 2048;

  f32x16 zero16 = {};
  f32x16 o2[2];
  o2[0] = zero16; o2[1] = zero16;
  f32x16 facc = zero16;           // MFMA row-sum accumulator (all rows equal)
  float m_run = -3.0e38f;

  int rloc = l >> 3;              // 0..7 row within chunk
  int swz = (l31 & 7);            // read-side XOR (row&7)
  int q3 = (l31 >> 3) & 3;        // read-side XOR ((row>>3)&3)

  auto STAGE = [&](int buf, int kv0) {
#pragma unroll
    for (int i = 0; i < 4; ++i) {
      int c = w * 4 + i;                   // 0..15; 0-7 = K chunks, 8-15 = V chunks
      int cc = c & 7;
      int row = cc * 8 + rloc;             // 0..63
      int sg = (((l & 7) ^ rloc ^ (cc & 3))) * 8;
      if (c < 8) {
        gload16(kbase + (size_t)(kv0 + row) * 512 + sg, &smem[buf][c * 512]);
      } else {
        gload16(vtb + (size_t)row * 2048 + kv0 + sg, &smem[buf][4096 + cc * 512]);
      }
    }
  };

  auto COMPUTE = [&](int buf) {
    const __bf16* Kt = &smem[buf][0];
    const __bf16* Vts = &smem[buf][4096];
    f32x16 sc[2];
#pragma unroll
    for (int kb = 0; kb < 2; ++kb) {
      sc[kb] = zero16;
      int r = kb * 32 + l31;
      __builtin_amdgcn_s_setprio(1);
#pragma unroll
      for (int dt = 0; dt < 4; ++dt) {
        bf16x8 kf = *(const bf16x8*)&Kt[r * 64 + ((dt * 2 + hi) ^ swz ^ q3) * 8];
        sc[kb] = mfma32(kf, qf[dt], sc[kb]);
      }
      __builtin_amdgcn_s_setprio(0);
    }

    float mx01 = -3.0e38f;
#pragma unroll
    for (int kb = 0; kb < 2; ++kb)
#pragma unroll
      for (int r = 0; r < 16; ++r) mx01 = fmaxf(mx01, sc[kb][r]);
    mx01 = fmaxf(mx01, __shfl_xor(mx01, 32));
    mx01 *= C2;
    if (!__all(mx01 <= m_run + THR)) {
      float mnew = fmaxf(m_run, mx01);
      float alpha = exp2f(m_run - mnew);
      m_run = mnew;
#pragma unroll
      for (int r = 0; r < 16; ++r) facc[r] *= alpha;
#pragma unroll
      for (int dblk = 0; dblk < 2; ++dblk)
#pragma unroll
        for (int r = 0; r < 16; ++r) o2[dblk][r] *= alpha;
    }
#pragma unroll
    for (int kb = 0; kb < 2; ++kb)
#pragma unroll
      for (int r = 0; r < 16; ++r)
        sc[kb][r] = exp2f(__builtin_fmaf(sc[kb][r], C2, -m_run));

#pragma unroll
    for (int t = 0; t < 4; ++t) {
      int kb = t >> 1, h8 = (t & 1) * 8;
      unsigned u0 = cvtpk(sc[kb][h8 + 0], sc[kb][h8 + 1]);
      unsigned u1 = cvtpk(sc[kb][h8 + 2], sc[kb][h8 + 3]);
      unsigned u2 = cvtpk(sc[kb][h8 + 4], sc[kb][h8 + 5]);
      unsigned u3 = cvtpk(sc[kb][h8 + 6], sc[kb][h8 + 7]);
      pl32swap(u0, u2);
      pl32swap(u1, u3);
      union { unsigned u[4]; bf16x8 v; } pb;
      pb.u[0] = u0; pb.u[1] = u1; pb.u[2] = u2; pb.u[3] = u3;
      __builtin_amdgcn_s_setprio(1);
      facc = mfma32(ones, pb.v, facc);   // row-sum of P on the MFMA pipe
#pragma unroll
      for (int dblk = 0; dblk < 2; ++dblk) {
        int r = dblk * 32 + l31;
        bf16x8 vf = *(const bf16x8*)&Vts[r * 64 + ((t * 2 + hi) ^ swz ^ q3) * 8];
        o2[dblk] = mfma32(vf, pb.v, o2[dblk]);
      }
      __builtin_amdgcn_s_setprio(0);
    }
  };

  STAGE(0, 0);
  STAGE(1, 64);
  int bc = 0, sb = 2;
  for (int t = 0; t < 31; ++t) {
    WAIT_VM(4);
    if (t < 30) { STAGE(sb, (t + 2) * 64); sb = sb == 2 ? 0 : sb + 1; }
    COMPUTE(bc); bc = bc == 2 ? 0 : bc + 1;
  }
  WAIT_VM(0);
  COMPUTE(bc);

  // --- epilogue: normalize, transpose O^T->O via LDS (per-wave region), store ---
  float invl = 1.0f / facc[0];
  __bf16* T = &smem[0][w * 2048];
  int swzq = (l31 & 7) * 8;
#pragma unroll
  for (int dblk = 0; dblk < 2; ++dblk)
#pragma unroll
    for (int g = 0; g < 4; ++g) {
      unsigned w0 = cvtpk(o2[dblk][g * 4 + 0] * invl, o2[dblk][g * 4 + 1] * invl);
      unsigned w1 = cvtpk(o2[dblk][g * 4 + 2] * invl, o2[dblk][g * 4 + 3] * invl);
      int d4 = dblk * 32 + g * 8 + hi * 4;
      uint2 pk2; pk2.x = w0; pk2.y = w1;
      *(uint2*)&T[l31 * 64 + (d4 ^ swzq)] = pk2;
    }
  int qr = l >> 1, hf = l & 1;
  int swzr = (qr & 7) * 8;
  __bf16* aorow = ao + (size_t)((b << 11) + q0w + qr) * 512 + hh * 64;
#pragma unroll
  for (int m = 0; m < 2; ++m) {
    int e = hf * 32 + m * 16;
    bf16x8 v0 = *(const bf16x8*)&T[qr * 64 + ((e) ^ swzr)];
    bf16x8 v1 = *(const bf16x8*)&T[qr * 64 + ((e + 8) ^ swzr)];
    *(bf16x8*)&aorow[e] = v0;
    *(bf16x8*)&aorow[e + 8] = v1;
  }
}

// ---------------- out projection + residual + transpose, BN=64 tiles (512 blocks, 2/CU) ----------------
__global__ __launch_bounds__(256) void gemm_proj(const __bf16* __restrict__ A, const __bf16* __restrict__ W,
                                                 const float* __restrict__ bias,
                                                 const float* __restrict__ resid,
                                                 float* __restrict__ outp) {
  __shared__ __align__(16) union UU {
    struct SS { __bf16 a[3][4096]; __bf16 b[3][2048]; } s;  // A:128x32 x3, B:64x32 x3
    float st[128 * 65];
  } u;
  int tid = threadIdx.x, wid = tid >> 6, l = tid & 63;
  int m0 = blockIdx.x * 128, n0 = blockIdx.y * 64;
  int wm = (wid >> 1) * 64, wn = (wid & 1) * 32;
  int l16 = l & 15, lg = l >> 4;
  f32x4 zero = {0.f, 0.f, 0.f, 0.f};
  f32x4 acc[4][2];
#pragma unroll
  for (int mt = 0; mt < 4; ++mt)
#pragma unroll
    for (int nt = 0; nt < 2; ++nt) acc[mt][nt] = zero;

  int srow = wid * 32 + (l >> 2);                 // A row (plus t*16)
  int brow = wid * 16 + (l >> 2);                 // B row
  int scol = ((l & 3) ^ ((l >> 3) & 3)) * 8;      // pre-swizzled global k-chunk
  int rs = (lg ^ ((l16 >> 1) & 3)) * 8;           // read-side phys slot

  auto STG = [&](int buf, int k0) {
#pragma unroll
    for (int t = 0; t < 2; ++t)
      gload16(A + (size_t)(m0 + srow + t * 16) * 512 + k0 + scol, &u.s.a[buf][(wid * 32 + t * 16) * 32]);
    gload16(W + (size_t)(n0 + brow) * 512 + k0 + scol, &u.s.b[buf][(wid * 16) * 32]);
  };
  auto CMP = [&](int buf) {
    bf16x8 af[4], bfr[2];
#pragma unroll
    for (int mt = 0; mt < 4; ++mt) af[mt] = *(const bf16x8*)&u.s.a[buf][(wm + mt * 16 + l16) * 32 + rs];
#pragma unroll
    for (int nt = 0; nt < 2; ++nt) bfr[nt] = *(const bf16x8*)&u.s.b[buf][(wn + nt * 16 + l16) * 32 + rs];
    __builtin_amdgcn_s_setprio(1);
#pragma unroll
    for (int mt = 0; mt < 4; ++mt)
#pragma unroll
      for (int nt = 0; nt < 2; ++nt) acc[mt][nt] = mfma16(af[mt], bfr[nt], acc[mt][nt]);
    __builtin_amdgcn_s_setprio(0);
  };

  STG(0, 0); STG(1, 32);
  int bc = 0, sb = 2;
  for (int t = 0; t < 15; ++t) {
    WAIT_VM(3);
    if (t < 14) { STG(sb, (t + 2) * 32); sb = sb == 2 ? 0 : sb + 1; }
    CMP(bc); bc = bc == 2 ? 0 : bc + 1;
  }
  WAIT_VM(0);
  CMP(bc);

  __syncthreads();
#pragma unroll
  for (int nt = 0; nt < 2; ++nt) {
    int col = wn + nt * 16 + l16;
    float bb = bias[n0 + col];
#pragma unroll
    for (int mt = 0; mt < 4; ++mt)
#pragma unroll
      for (int r = 0; r < 4; ++r)
        u.st[(wm + mt * 16 + lg * 4 + r) * 65 + col] = acc[mt][nt][r] + bb;
  }
  __syncthreads();
  int b = m0 >> 11;
  int sbase = m0 & 2047;
  const float* rb = resid + ((size_t)b << 20);
  float* ob = outp + ((size_t)b << 20);
#pragma unroll
  for (int it = 0; it < 8; ++it) {
    int c = (tid >> 5) + it * 8;  // 0..63 local col
    int s4 = (tid & 31) * 4;      // 0..124 local row
    float4 r4 = *(const float4*)&rb[(size_t)(n0 + c) * 2048 + sbase + s4];
    float4 o4;
    o4.x = u.st[(s4 + 0) * 65 + c] + r4.x;
    o4.y = u.st[(s4 + 1) * 65 + c] + r4.y;
    o4.z = u.st[(s4 + 2) * 65 + c] + r4.z;
    o4.w = u.st[(s4 + 3) * 65 + c] + r4.w;
    *(float4*)&ob[(size_t)(n0 + c) * 2048 + sbase + s4] = o4;
  }
}

extern "C" void kernel_launch(void* const* d_in, const int* in_sizes, int n_in,
                              void* d_out, int out_size, void* d_ws, size_t ws_size,
                              hipStream_t stream) {
  const float* x   = (const float*)d_in[0];
  const float* gw  = (const float*)d_in[1];
  const float* gb  = (const float*)d_in[2];
  const float* wqf = (const float*)d_in[3];
  const float* bqf = (const float*)d_in[4];
  const float* wkf = (const float*)d_in[5];
  const float* bkf = (const float*)d_in[6];
  const float* wvf = (const float*)d_in[7];
  const float* bvf = (const float*)d_in[8];
  const float* wof = (const float*)d_in[9];
  const float* bof = (const float*)d_in[10];
  float* outp = (float*)d_out;

  char* ws = (char*)d_ws;
  float* stats = (float*)ws;              // 512 floats of partials
  const size_t MAT = (size_t)8192 * 512;  // elements
  __bf16* h  = (__bf16*)(ws + 4096);
  __bf16* q  = h + MAT;
  __bf16* k  = q + MAT;
  __bf16* vt = k + MAT;
  __bf16* ao = vt + MAT;
  __bf16* wB = ao + MAT;  // 4 x 512*512

  gn_partial<<<dim3(64, 4), 256, 0, stream>>>(x, stats);
  norm_tr<<<dim3(32, 8, 4), 256, 0, stream>>>(x, gw, gb, stats, h);
  wcvt<<<1024, 256, 0, stream>>>(wqf, wkf, wvf, wof, wB);
  gemm_qkv<<<dim3(64, 4, 3), 256, 0, stream>>>(h, wB, bqf, bkf, bvf, q, k, vt);
  attn<<<dim3(16, 8, 4), 256, 0, stream>>>(q, k, vt, ao);
  gemm_proj<<<dim3(64, 8), 256, 0, stream>>>(ao, wB + 3 * 262144, bof, x, outp);
}

// Round 11
// 189.166 us; speedup vs baseline: 1.0926x; 1.0135x over previous
//
#include <hip/hip_runtime.h>

typedef __attribute__((ext_vector_type(8))) __bf16 bf16x8;
typedef __attribute__((ext_vector_type(4))) __bf16 bf16x4;
typedef __attribute__((ext_vector_type(4))) float f32x4;
typedef __attribute__((ext_vector_type(16))) float f32x16;

#define BSZ 4
#define CCH 512
#define SEQ 2048
#define NH  8
#define HD  64

__device__ __forceinline__ f32x4 mfma16(bf16x8 a, bf16x8 b, f32x4 c) {
  return __builtin_amdgcn_mfma_f32_16x16x32_bf16(a, b, c, 0, 0, 0);
}
__device__ __forceinline__ f32x16 mfma32(bf16x8 a, bf16x8 b, f32x16 c) {
  return __builtin_amdgcn_mfma_f32_32x32x16_bf16(a, b, c, 0, 0, 0);
}

__device__ __forceinline__ void gload16(const void* g, void* l) {
  __builtin_amdgcn_global_load_lds((const __attribute__((address_space(1))) void*)g,
                                   (__attribute__((address_space(3))) void*)l,
                                   16, 0, 0);
}

__device__ __forceinline__ unsigned cvtpk(float lo, float hi) {
  unsigned r;
  asm("v_cvt_pk_bf16_f32 %0, %1, %2" : "=v"(r) : "v"(lo), "v"(hi));
  return r;
}
__device__ __forceinline__ void pl32swap(unsigned& a, unsigned& b) {
  asm("v_permlane32_swap_b32 %0, %1" : "+v"(a), "+v"(b));
}

#define WAIT_VM(N)                                          \
  asm volatile("s_waitcnt vmcnt(" #N ")" ::: "memory");     \
  __builtin_amdgcn_sched_barrier(0);                        \
  __builtin_amdgcn_s_barrier();

// ---------------- fused: GroupNorm partials (blocks 0..255) + weight cvt (blocks 256..1279) ----------------
__global__ __launch_bounds__(256) void gn_wcvt(const float* __restrict__ x,
                                               const float* __restrict__ wq, const float* __restrict__ wk,
                                               const float* __restrict__ wv, const float* __restrict__ wo,
                                               float* __restrict__ stats, __bf16* __restrict__ wB) {
  int bid = blockIdx.x;
  int tid = threadIdx.x;
  if (bid < 256) {
    int b = bid >> 6, xc = bid & 63;
    const float4* xb = (const float4*)(x + ((size_t)b << 20) + (size_t)xc * 16384);
    float s = 0.f, sq = 0.f;
#pragma unroll
    for (int i = 0; i < 16; ++i) {
      float4 v = xb[i * 256 + tid];
      s  += v.x + v.y + v.z + v.w;
      sq += v.x * v.x + v.y * v.y + v.z * v.z + v.w * v.w;
    }
#pragma unroll
    for (int o = 32; o > 0; o >>= 1) { s += __shfl_down(s, o); sq += __shfl_down(sq, o); }
    __shared__ float ls[4], lq[4];
    int w = tid >> 6;
    if ((tid & 63) == 0) { ls[w] = s; lq[w] = sq; }
    __syncthreads();
    if (tid == 0) {
      stats[b * 64 + xc]       = ls[0] + ls[1] + ls[2] + ls[3];
      stats[256 + b * 64 + xc] = lq[0] + lq[1] + lq[2] + lq[3];
    }
  } else {
    int i = (bid - 256) * 256 + tid;  // 0..262143
    wB[i]          = (__bf16)wq[i];
    wB[262144 + i] = (__bf16)wk[i];
    wB[524288 + i] = (__bf16)wv[i];
    wB[786432 + i] = (__bf16)wo[i];
  }
}

// ---------------- normalize + transpose to [B*S, C] bf16 (gn_final fused) ----------------
__global__ __launch_bounds__(256) void norm_tr(const float* __restrict__ x,
                                               const float* __restrict__ gw,
                                               const float* __restrict__ gb,
                                               const float* __restrict__ stats,
                                               __bf16* __restrict__ h) {
  int s0 = blockIdx.x * 64, c0 = blockIdx.y * 64, b = blockIdx.z;
  float sacc = 0.f, qacc = 0.f;
  for (int i = 0; i < 64; ++i) {
    sacc += stats[b * 64 + i];
    qacc += stats[256 + b * 64 + i];
  }
  const float inv_n = 1.0f / 1048576.f;
  float mean = sacc * inv_n;
  float rstd = rsqrtf(qacc * inv_n - mean * mean + 1e-5f);
  const float* xb = x + ((size_t)b << 20);
  __shared__ __align__(16) __bf16 tile[64][72];
  int tid = threadIdx.x;
#pragma unroll
  for (int j = 0; j < 16; ++j) {
    int e = tid + j * 256;
    int cl = e >> 6, sl = e & 63;
    float vv = xb[(size_t)(c0 + cl) * 2048 + s0 + sl];
    float hn = (vv - mean) * rstd * gw[c0 + cl] + gb[c0 + cl];
    tile[cl][sl] = (__bf16)hn;
  }
  __syncthreads();
#pragma unroll
  for (int j = 0; j < 2; ++j) {
    int row = (tid >> 3) + j * 32;  // s-local
    int cg = tid & 7;
    bf16x8 pk;
#pragma unroll
    for (int e = 0; e < 8; ++e) pk[e] = tile[cg * 8 + e][row];
    *(bf16x8*)&h[(size_t)((b << 11) + s0 + row) * 512 + c0 + cg * 8] = pk;
  }
}

// ---------------- QKV GEMM: [8192,512] x [512,512]^T, BK=32, 3-buf counted pipeline ----------------
// 1-D grid 768, XCD-swizzled: flat = x + 64*(y + 4*z) -> same-A-tile blocks share an XCD L2.
// z==2 writes V^T [B,H,D,S] via LDS transpose (coalesced stores).
__global__ __launch_bounds__(256) void gemm_qkv(const __bf16* __restrict__ A, const __bf16* __restrict__ Wb,
                                                const float* __restrict__ bq, const float* __restrict__ bk,
                                                const float* __restrict__ bvv,
                                                __bf16* __restrict__ oq, __bf16* __restrict__ ok,
                                                __bf16* __restrict__ ovt) {
  __shared__ __align__(16) union QU {
    struct SS { __bf16 a[3][4096]; __bf16 b[3][4096]; } s;
    __bf16 t[128 * 136];
  } u;
  int flat = blockIdx.x;
  int xm = flat & 63, e = flat >> 6;
  int yn = e & 3, z = e >> 2;
  const __bf16* W = Wb + (size_t)z * 262144;
  const float* bias = z == 0 ? bq : (z == 1 ? bk : bvv);
  int tid = threadIdx.x, wid = tid >> 6, l = tid & 63;
  int m0 = xm * 128, n0 = yn * 128;
  int wm = (wid >> 1) * 64, wn = (wid & 1) * 64;
  int l16 = l & 15, lg = l >> 4;
  f32x4 zero = {0.f, 0.f, 0.f, 0.f};
  f32x4 acc[4][4];
#pragma unroll
  for (int mt = 0; mt < 4; ++mt)
#pragma unroll
    for (int nt = 0; nt < 4; ++nt) acc[mt][nt] = zero;

  int srow = wid * 32 + (l >> 2);                 // row within 128-tile (plus t*16)
  int scol = ((l & 3) ^ ((l >> 3) & 3)) * 8;      // pre-swizzled global k-chunk
  int rs = (lg ^ ((l16 >> 1) & 3)) * 8;           // read-side phys slot

  auto STG = [&](int buf, int k0) {
#pragma unroll
    for (int t = 0; t < 2; ++t) {
      gload16(A + (size_t)(m0 + srow + t * 16) * 512 + k0 + scol, &u.s.a[buf][(wid * 32 + t * 16) * 32]);
      gload16(W + (size_t)(n0 + srow + t * 16) * 512 + k0 + scol, &u.s.b[buf][(wid * 32 + t * 16) * 32]);
    }
  };
  auto CMP = [&](int buf) {
    bf16x8 af[4], bfr[4];
#pragma unroll
    for (int mt = 0; mt < 4; ++mt) af[mt] = *(const bf16x8*)&u.s.a[buf][(wm + mt * 16 + l16) * 32 + rs];
#pragma unroll
    for (int nt = 0; nt < 4; ++nt) bfr[nt] = *(const bf16x8*)&u.s.b[buf][(wn + nt * 16 + l16) * 32 + rs];
    __builtin_amdgcn_s_setprio(1);
#pragma unroll
    for (int mt = 0; mt < 4; ++mt)
#pragma unroll
      for (int nt = 0; nt < 4; ++nt) acc[mt][nt] = mfma16(af[mt], bfr[nt], acc[mt][nt]);
    __builtin_amdgcn_s_setprio(0);
  };

  STG(0, 0); STG(1, 32);
  int bc = 0, sb = 2;
  for (int t = 0; t < 15; ++t) {
    WAIT_VM(4);
    if (t < 14) { STG(sb, (t + 2) * 32); sb = sb == 2 ? 0 : sb + 1; }
    CMP(bc); bc = bc == 2 ? 0 : bc + 1;
  }
  WAIT_VM(0);
  CMP(bc);

  if (z < 2) {
    __bf16* out = z == 0 ? oq : ok;
#pragma unroll
    for (int nt = 0; nt < 4; ++nt) {
      int col = n0 + wn + nt * 16 + l16;
      float bb = bias[col];
#pragma unroll
      for (int mt = 0; mt < 4; ++mt)
#pragma unroll
        for (int r = 0; r < 4; ++r)
          out[(size_t)(m0 + wm + mt * 16 + lg * 4 + r) * 512 + col] = (__bf16)(acc[mt][nt][r] + bb);
    }
  } else {
    __syncthreads();
    // stage transposed: t[col][m], stride 136 (keeps 16B alignment for b128)
#pragma unroll
    for (int nt = 0; nt < 4; ++nt) {
      int col = wn + nt * 16 + l16;
      float bb = bias[n0 + col];
#pragma unroll
      for (int mt = 0; mt < 4; ++mt)
#pragma unroll
        for (int r = 0; r < 4; ++r)
          u.t[col * 136 + wm + mt * 16 + lg * 4 + r] = (__bf16)(acc[mt][nt][r] + bb);
    }
    __syncthreads();
    int bI = m0 >> 11, sbase = m0 & 2047;
#pragma unroll
    for (int p = 0; p < 8; ++p) {
      int row = (tid >> 4) + p * 16;     // local col of C = d index
      int ck = tid & 15;
      bf16x8 v = *(const bf16x8*)&u.t[row * 136 + ck * 8];
      int colg = n0 + row;
      int hd = colg >> 6, dd = colg & 63;
      *(bf16x8*)&ovt[((size_t)((bI * 8 + hd) * 64 + dd)) * 2048 + sbase + ck * 8] = v;
    }
  }
}

// ---------------- flash attention: LDS-staged K/V, 3-buf counted-vmcnt, MFMA row-sum ----------------
// 1-D grid 512, XCD-swizzled: flat = h + 8*(b + 4*x) -> the 16 q-blocks sharing one (b,h)'s
// K/V land on XCD h; per-XCD K/V+Q working set ~3MB fits the 4MB L2.
__global__ __launch_bounds__(256) void attn(const __bf16* __restrict__ q, const __bf16* __restrict__ k,
                                            const __bf16* __restrict__ vt, __bf16* __restrict__ ao) {
  const float C2 = 0.18033688011f;  // (1/8) * log2(e)
  const float THR = 8.0f;           // defer-max threshold (log2 units)
  int tid = threadIdx.x, w = tid >> 6, l = tid & 63;
  int flat = blockIdx.x;
  int hh = flat & 7;
  int inner = flat >> 3;
  int b = inner & 3;
  int q0w = (inner >> 2) * 128 + w * 32;
  int l31 = l & 31, hi = l >> 5;

  __shared__ __align__(16) __bf16 smem[3][8192];  // per buf: K[64][64] | V[64][64]

  bf16x8 qf[4];
  {
    const __bf16* qrow = q + ((size_t)((b << 11) + q0w + l31)) * 512 + hh * 64 + hi * 8;
#pragma unroll
    for (int dt = 0; dt < 4; ++dt) qf[dt] = *(const bf16x8*)&qrow[dt * 16];
  }
  bf16x8 ones;
#pragma unroll
  for (int j = 0; j < 8; ++j) ones[j] = (__bf16)1.0f;

  const __bf16* kbase = k + ((size_t)(b << 11)) * 512 + hh * 64;
  const __bf16* vtb = vt + ((size_t)((b * 8 + hh) * 64)) * 2048;

  f32x16 zero16 = {};
  f32x16 o2[2];
  o2[0] = zero16; o2[1] = zero16;
  f32x16 facc = zero16;           // MFMA row-sum accumulator (all rows equal)
  float m_run = -3.0e38f;

  int rloc = l >> 3;              // 0..7 row within chunk
  int swz = (l31 & 7);            // read-side XOR (row&7)
  int q3 = (l31 >> 3) & 3;        // read-side XOR ((row>>3)&3)

  auto STAGE = [&](int buf, int kv0) {
#pragma unroll
    for (int i = 0; i < 4; ++i) {
      int c = w * 4 + i;                   // 0..15; 0-7 = K chunks, 8-15 = V chunks
      int cc = c & 7;
      int row = cc * 8 + rloc;             // 0..63
      int sg = (((l & 7) ^ rloc ^ (cc & 3))) * 8;
      if (c < 8) {
        gload16(kbase + (size_t)(kv0 + row) * 512 + sg, &smem[buf][c * 512]);
      } else {
        gload16(vtb + (size_t)row * 2048 + kv0 + sg, &smem[buf][4096 + cc * 512]);
      }
    }
  };

  auto COMPUTE = [&](int buf) {
    const __bf16* Kt = &smem[buf][0];
    const __bf16* Vts = &smem[buf][4096];
    f32x16 sc[2];
#pragma unroll
    for (int kb = 0; kb < 2; ++kb) {
      sc[kb] = zero16;
      int r = kb * 32 + l31;
      __builtin_amdgcn_s_setprio(1);
#pragma unroll
      for (int dt = 0; dt < 4; ++dt) {
        bf16x8 kf = *(const bf16x8*)&Kt[r * 64 + ((dt * 2 + hi) ^ swz ^ q3) * 8];
        sc[kb] = mfma32(kf, qf[dt], sc[kb]);
      }
      __builtin_amdgcn_s_setprio(0);
    }

    float mx01 = -3.0e38f;
#pragma unroll
    for (int kb = 0; kb < 2; ++kb)
#pragma unroll
      for (int r = 0; r < 16; ++r) mx01 = fmaxf(mx01, sc[kb][r]);
    mx01 = fmaxf(mx01, __shfl_xor(mx01, 32));
    mx01 *= C2;
    if (!__all(mx01 <= m_run + THR)) {
      float mnew = fmaxf(m_run, mx01);
      float alpha = exp2f(m_run - mnew);
      m_run = mnew;
#pragma unroll
      for (int r = 0; r < 16; ++r) facc[r] *= alpha;
#pragma unroll
      for (int dblk = 0; dblk < 2; ++dblk)
#pragma unroll
        for (int r = 0; r < 16; ++r) o2[dblk][r] *= alpha;
    }
#pragma unroll
    for (int kb = 0; kb < 2; ++kb)
#pragma unroll
      for (int r = 0; r < 16; ++r)
        sc[kb][r] = exp2f(__builtin_fmaf(sc[kb][r], C2, -m_run));

#pragma unroll
    for (int t = 0; t < 4; ++t) {
      int kb = t >> 1, h8 = (t & 1) * 8;
      unsigned u0 = cvtpk(sc[kb][h8 + 0], sc[kb][h8 + 1]);
      unsigned u1 = cvtpk(sc[kb][h8 + 2], sc[kb][h8 + 3]);
      unsigned u2 = cvtpk(sc[kb][h8 + 4], sc[kb][h8 + 5]);
      unsigned u3 = cvtpk(sc[kb][h8 + 6], sc[kb][h8 + 7]);
      pl32swap(u0, u2);
      pl32swap(u1, u3);
      union { unsigned u[4]; bf16x8 v; } pb;
      pb.u[0] = u0; pb.u[1] = u1; pb.u[2] = u2; pb.u[3] = u3;
      __builtin_amdgcn_s_setprio(1);
      facc = mfma32(ones, pb.v, facc);   // row-sum of P on the MFMA pipe
#pragma unroll
      for (int dblk = 0; dblk < 2; ++dblk) {
        int r = dblk * 32 + l31;
        bf16x8 vf = *(const bf16x8*)&Vts[r * 64 + ((t * 2 + hi) ^ swz ^ q3) * 8];
        o2[dblk] = mfma32(vf, pb.v, o2[dblk]);
      }
      __builtin_amdgcn_s_setprio(0);
    }
  };

  STAGE(0, 0);
  STAGE(1, 64);
  int bc = 0, sb = 2;
  for (int t = 0; t < 31; ++t) {
    WAIT_VM(4);
    if (t < 30) { STAGE(sb, (t + 2) * 64); sb = sb == 2 ? 0 : sb + 1; }
    COMPUTE(bc); bc = bc == 2 ? 0 : bc + 1;
  }
  WAIT_VM(0);
  COMPUTE(bc);

  // --- epilogue: normalize, transpose O^T->O via LDS (per-wave region), store ---
  float invl = 1.0f / facc[0];
  __bf16* T = &smem[0][w * 2048];
  int swzq = (l31 & 7) * 8;
#pragma unroll
  for (int dblk = 0; dblk < 2; ++dblk)
#pragma unroll
    for (int g = 0; g < 4; ++g) {
      unsigned w0 = cvtpk(o2[dblk][g * 4 + 0] * invl, o2[dblk][g * 4 + 1] * invl);
      unsigned w1 = cvtpk(o2[dblk][g * 4 + 2] * invl, o2[dblk][g * 4 + 3] * invl);
      int d4 = dblk * 32 + g * 8 + hi * 4;
      uint2 pk2; pk2.x = w0; pk2.y = w1;
      *(uint2*)&T[l31 * 64 + (d4 ^ swzq)] = pk2;
    }
  int qr = l >> 1, hf = l & 1;
  int swzr = (qr & 7) * 8;
  __bf16* aorow = ao + (size_t)((b << 11) + q0w + qr) * 512 + hh * 64;
#pragma unroll
  for (int m = 0; m < 2; ++m) {
    int e = hf * 32 + m * 16;
    bf16x8 v0 = *(const bf16x8*)&T[qr * 64 + ((e) ^ swzr)];
    bf16x8 v1 = *(const bf16x8*)&T[qr * 64 + ((e + 8) ^ swzr)];
    *(bf16x8*)&aorow[e] = v0;
    *(bf16x8*)&aorow[e + 8] = v1;
  }
}

// ---------------- out projection + residual + transpose, BN=64, XCD-swizzled 1-D grid ----------------
// flat = (x&7) + 8*((x>>3) + 8*y): same-A-tile blocks share an XCD L2.
__global__ __launch_bounds__(256) void gemm_proj(const __bf16* __restrict__ A, const __bf16* __restrict__ W,
                                                 const float* __restrict__ bias,
                                                 const float* __restrict__ resid,
                                                 float* __restrict__ outp) {
  __shared__ __align__(16) union UU {
    struct SS { __bf16 a[3][4096]; __bf16 b[3][2048]; } s;  // A:128x32 x3, B:64x32 x3
    float st[128 * 65];
  } u;
  int flat = blockIdx.x;
  int x7 = flat & 7;
  int inner = flat >> 3;
  int xm = ((inner & 7) << 3) | x7;
  int yn = inner >> 3;
  int tid = threadIdx.x, wid = tid >> 6, l = tid & 63;
  int m0 = xm * 128, n0 = yn * 64;
  int wm = (wid >> 1) * 64, wn = (wid & 1) * 32;
  int l16 = l & 15, lg = l >> 4;
  f32x4 zero = {0.f, 0.f, 0.f, 0.f};
  f32x4 acc[4][2];
#pragma unroll
  for (int mt = 0; mt < 4; ++mt)
#pragma unroll
    for (int nt = 0; nt < 2; ++nt) acc[mt][nt] = zero;

  int srow = wid * 32 + (l >> 2);                 // A row (plus t*16)
  int brow = wid * 16 + (l >> 2);                 // B row
  int scol = ((l & 3) ^ ((l >> 3) & 3)) * 8;      // pre-swizzled global k-chunk
  int rs = (lg ^ ((l16 >> 1) & 3)) * 8;           // read-side phys slot

  auto STG = [&](int buf, int k0) {
#pragma unroll
    for (int t = 0; t < 2; ++t)
      gload16(A + (size_t)(m0 + srow + t * 16) * 512 + k0 + scol, &u.s.a[buf][(wid * 32 + t * 16) * 32]);
    gload16(W + (size_t)(n0 + brow) * 512 + k0 + scol, &u.s.b[buf][(wid * 16) * 32]);
  };
  auto CMP = [&](int buf) {
    bf16x8 af[4], bfr[2];
#pragma unroll
    for (int mt = 0; mt < 4; ++mt) af[mt] = *(const bf16x8*)&u.s.a[buf][(wm + mt * 16 + l16) * 32 + rs];
#pragma unroll
    for (int nt = 0; nt < 2; ++nt) bfr[nt] = *(const bf16x8*)&u.s.b[buf][(wn + nt * 16 + l16) * 32 + rs];
    __builtin_amdgcn_s_setprio(1);
#pragma unroll
    for (int mt = 0; mt < 4; ++mt)
#pragma unroll
      for (int nt = 0; nt < 2; ++nt) acc[mt][nt] = mfma16(af[mt], bfr[nt], acc[mt][nt]);
    __builtin_amdgcn_s_setprio(0);
  };

  STG(0, 0); STG(1, 32);
  int bc = 0, sb = 2;
  for (int t = 0; t < 15; ++t) {
    WAIT_VM(3);
    if (t < 14) { STG(sb, (t + 2) * 32); sb = sb == 2 ? 0 : sb + 1; }
    CMP(bc); bc = bc == 2 ? 0 : bc + 1;
  }
  WAIT_VM(0);
  CMP(bc);

  __syncthreads();
#pragma unroll
  for (int nt = 0; nt < 2; ++nt) {
    int col = wn + nt * 16 + l16;
    float bb = bias[n0 + col];
#pragma unroll
    for (int mt = 0; mt < 4; ++mt)
#pragma unroll
      for (int r = 0; r < 4; ++r)
        u.st[(wm + mt * 16 + lg * 4 + r) * 65 + col] = acc[mt][nt][r] + bb;
  }
  __syncthreads();
  int b = m0 >> 11;
  int sbase = m0 & 2047;
  const float* rb = resid + ((size_t)b << 20);
  float* ob = outp + ((size_t)b << 20);
#pragma unroll
  for (int it = 0; it < 8; ++it) {
    int c = (tid >> 5) + it * 8;  // 0..63 local col
    int s4 = (tid & 31) * 4;      // 0..124 local row
    float4 r4 = *(const float4*)&rb[(size_t)(n0 + c) * 2048 + sbase + s4];
    float4 o4;
    o4.x = u.st[(s4 + 0) * 65 + c] + r4.x;
    o4.y = u.st[(s4 + 1) * 65 + c] + r4.y;
    o4.z = u.st[(s4 + 2) * 65 + c] + r4.z;
    o4.w = u.st[(s4 + 3) * 65 + c] + r4.w;
    *(float4*)&ob[(size_t)(n0 + c) * 2048 + sbase + s4] = o4;
  }
}

extern "C" void kernel_launch(void* const* d_in, const int* in_sizes, int n_in,
                              void* d_out, int out_size, void* d_ws, size_t ws_size,
                              hipStream_t stream) {
  const float* x   = (const float*)d_in[0];
  const float* gw  = (const float*)d_in[1];
  const float* gb  = (const float*)d_in[2];
  const float* wqf = (const float*)d_in[3];
  const float* bqf = (const float*)d_in[4];
  const float* wkf = (const float*)d_in[5];
  const float* bkf = (const float*)d_in[6];
  const float* wvf = (const float*)d_in[7];
  const float* bvf = (const float*)d_in[8];
  const float* wof = (const float*)d_in[9];
  const float* bof = (const float*)d_in[10];
  float* outp = (float*)d_out;

  char* ws = (char*)d_ws;
  float* stats = (float*)ws;              // 512 floats of partials
  const size_t MAT = (size_t)8192 * 512;  // elements
  __bf16* h  = (__bf16*)(ws + 4096);
  __bf16* q  = h + MAT;
  __bf16* k  = q + MAT;
  __bf16* vt = k + MAT;
  __bf16* ao = vt + MAT;
  __bf16* wB = ao + MAT;  // 4 x 512*512

  gn_wcvt<<<1280, 256, 0, stream>>>(x, wqf, wkf, wvf, wof, stats, wB);
  norm_tr<<<dim3(32, 8, 4), 256, 0, stream>>>(x, gw, gb, stats, h);
  gemm_qkv<<<768, 256, 0, stream>>>(h, wB, bqf, bkf, bvf, q, k, vt);
  attn<<<512, 256, 0, stream>>>(q, k, vt, ao);
  gemm_proj<<<512, 256, 0, stream>>>(ao, wB + 3 * 262144, bof, x, outp);
}